// Round 17
// baseline (75.458 us; speedup 1.0000x reference)
//
#include <hip/hip_runtime.h>
#include <math.h>

#define BATCH 4
#define LSEQ 2048
#define BL (BATCH*LSEQ)        // 8192
#define DMODEL 256
#define DINNER 512
#define NSTATE 16
#define DTRANK 16
#define NPROJ 48               // DTRANK + 2*NSTATE
#define HORIZ 96
#define NCH 32                 // scan chunks
#define TCH (LSEQ/NCH)         // 64
#define PSTRIDE (BL*NPROJ)     // 393216 (part jp-stride)

typedef __attribute__((ext_vector_type(8))) short short8b;  // 8 bf16
typedef __attribute__((ext_vector_type(4))) short short4b;  // 4 bf16
typedef __attribute__((ext_vector_type(4))) float f32x4;

__device__ __forceinline__ unsigned short f2bf(float f) {
  unsigned u = __float_as_uint(f);
  u += 0x7FFF + ((u >> 16) & 1);          // round-to-nearest-even
  return (unsigned short)(u >> 16);
}
__device__ __forceinline__ float bf2f(unsigned short h) {
  return __uint_as_float(((unsigned)h) << 16);
}

// ===== kernel 1 (fused): in_proj(x half, bf16 MFMA) + conv + silu -> uT(bf16) ; x_dbl via MFMA =====
// grid 512 main (btc = bx&255, jp = bx>>8 so jp pairs share an XCD) + 64 hwf side-job; 512 thr.
// LDS 35.5KB (no sw2b: xdbl B-frags load straight from L2-resident xpw) -> 4 blocks/CU.
__global__ __launch_bounds__(512) void k_front(const float* __restrict__ X,
                                               const float* __restrict__ W,
                                               const float* __restrict__ cw,
                                               const float* __restrict__ cb,
                                               const float* __restrict__ xpw,
                                               const float* __restrict__ opw,
                                               const float* __restrict__ hw,
                                               unsigned short* __restrict__ uTb,
                                               float* __restrict__ part,
                                               float* __restrict__ hwf) {
  __shared__ unsigned short sBX[48 * 264];    // [tok][33*8] bf16, row 528B (25.3KB)
  __shared__ unsigned short u_ldsb[128 * 40]; // [j_local][tok] bf16, row 80B (10.2KB)
  const int tid = threadIdx.x;
  const int bx = blockIdx.x;
  if (bx >= 512) {                 // ---- side-job: hwf[t][k] = sum_m hw[t][m]*opw[m][k]
    const int fid = bx - 512;      // 0..63
    const int k0 = fid * 8;
    float* scratch = (float*)sBX;  // [m 0..255][8] fp32 (8KB of the 25KB region)
    {
      int m = tid >> 1;            // opw rows = DMODEL = 256
      int half = (tid & 1) << 2;
      *(float4*)&scratch[m * 8 + half] =
        *(const float4*)&opw[(size_t)m * DINNER + k0 + half];
    }
    __syncthreads();
    for (int u = tid; u < HORIZ * 8; u += 512) {
      int t = u >> 3, kk = u & 7;
      const float* hr = &hw[(size_t)t * DMODEL];
      float acc = 0.f;
      #pragma unroll 8
      for (int m = 0; m < DMODEL; ++m) acc = fmaf(hr[m], scratch[m*8 + kk], acc);
      hwf[(size_t)t * DINNER + k0 + kk] = acc;
    }
    return;
  }
  const int btc = bx & 255;        // token tile
  const int jp  = bx >> 8;         // j-half; pair (bx, bx+256) -> same XCD (256 % 8 == 0)
  const int bt0 = btc * 32;
  const bool edge0 = ((bt0 & (LSEQ - 1)) == 0);
  const int lane = tid & 63;
  const int w  = tid >> 6;         // wave 0..7
  const int fl = lane & 15;
  const int fg = lane >> 4;        // 0..3
  // ---- phase 0: stage X tile bf16, tokens [bt0-16, bt0+32): sBX[tok][ko*8]
  for (int u = tid; u < 1536; u += 512) {
    int tok = u >> 5, ko = u & 31;
    int g = bt0 - 16 + tok;
    if (g < 0) g = 0;              // clamped rows feed only the (zeroed) halo frag
    const float* xr = &X[(size_t)g * DMODEL + ko * 8];
    float4 a = *(const float4*)xr, b = *(const float4*)(xr + 4);
    unsigned short t8[8] = {f2bf(a.x), f2bf(a.y), f2bf(a.z), f2bf(a.w),
                            f2bf(b.x), f2bf(b.y), f2bf(b.z), f2bf(b.w)};
    *(short8b*)&sBX[tok * 264 + ko * 8] = *(short8b*)t8;
  }
  const int sj = tid >> 2;         // uT write: j row
  const int sk = tid & 3;          // uT write: token-octet
  const int tf = w & 1;            // xdbl: token-frag (w<6)
  const int of = w >> 1;           // xdbl: o-frag
  f32x4 xacc = {0.f, 0.f, 0.f, 0.f};
  for (int jc = 0; jc < 2; ++jc) {
    const int jbase = jp * 256 + jc * 128;
    __syncthreads();               // prev jc done with u_ldsb; jc=0: sBX visible
    // W fragments -> registers (L2-resident; no LDS, no barriers)
    short8b aw[8];
    {
      const float* wrow = &W[(size_t)(jbase + w * 16 + fl) * DMODEL + fg * 8];
      #pragma unroll
      for (int ks = 0; ks < 8; ++ks) {
        float4 a = *(const float4*)(wrow + ks * 32);
        float4 b = *(const float4*)(wrow + ks * 32 + 4);
        unsigned short t8[8] = {f2bf(a.x), f2bf(a.y), f2bf(a.z), f2bf(a.w),
                                f2bf(b.x), f2bf(b.y), f2bf(b.z), f2bf(b.w)};
        aw[ks] = *(short8b*)t8;
      }
    }
    f32x4 acc0 = {0,0,0,0}, acc1 = {0,0,0,0}, acc2 = {0,0,0,0};
    #pragma unroll
    for (int ks = 0; ks < 8; ++ks) {
      const int kcol = (ks * 4 + fg) * 8;
      short8b x0 = *(short8b*)&sBX[(fl)      * 264 + kcol];
      short8b x1 = *(short8b*)&sBX[(16 + fl) * 264 + kcol];
      short8b x2 = *(short8b*)&sBX[(32 + fl) * 264 + kcol];
      acc0 = __builtin_amdgcn_mfma_f32_16x16x32_bf16(x0, aw[ks], acc0, 0, 0, 0);
      acc1 = __builtin_amdgcn_mfma_f32_16x16x32_bf16(x1, aw[ks], acc1, 0, 0, 0);
      acc2 = __builtin_amdgcn_mfma_f32_16x16x32_bf16(x2, aw[ks], acc2, 0, 0, 0);
    }
    // ---- conv + silu in registers (verified structure)
    if (edge0) acc0 = (f32x4){0,0,0,0};   // zero-pad halo at batch starts
    const int j = jbase + w * 16 + fl;
    const float4 cwv = *(const float4*)&cw[j * 4];
    const float cbv = cb[j];
    float u1[4], u2[4];
    {
      float s3a = __shfl(acc1[3], lane - 16), s3b = __shfl(acc0[3], lane + 48);
      float s2a = __shfl(acc1[2], lane - 16), s2b = __shfl(acc0[2], lane + 48);
      float s1a = __shfl(acc1[1], lane - 16), s1b = __shfl(acc0[1], lane + 48);
      float p1 = fg ? s3a : s3b, p2 = fg ? s2a : s2b, p3 = fg ? s1a : s1b;
      float xm1[4] = {p1, acc1[0], acc1[1], acc1[2]};
      float xm2[4] = {p2, p1, acc1[0], acc1[1]};
      float xm3[4] = {p3, p2, p1, acc1[0]};
      #pragma unroll
      for (int r = 0; r < 4; ++r) {
        float s = cbv;
        s = fmaf(cwv.x, xm3[r], s); s = fmaf(cwv.y, xm2[r], s);
        s = fmaf(cwv.z, xm1[r], s); s = fmaf(cwv.w, acc1[r], s);
        u1[r] = s / (1.f + __expf(-s));
      }
    }
    {
      float s3a = __shfl(acc2[3], lane - 16), s3b = __shfl(acc1[3], lane + 48);
      float s2a = __shfl(acc2[2], lane - 16), s2b = __shfl(acc1[2], lane + 48);
      float s1a = __shfl(acc2[1], lane - 16), s1b = __shfl(acc1[1], lane + 48);
      float p1 = fg ? s3a : s3b, p2 = fg ? s2a : s2b, p3 = fg ? s1a : s1b;
      float xm1[4] = {p1, acc2[0], acc2[1], acc2[2]};
      float xm2[4] = {p2, p1, acc2[0], acc2[1]};
      float xm3[4] = {p3, p2, p1, acc2[0]};
      #pragma unroll
      for (int r = 0; r < 4; ++r) {
        float s = cbv;
        s = fmaf(cwv.x, xm3[r], s); s = fmaf(cwv.y, xm2[r], s);
        s = fmaf(cwv.z, xm1[r], s); s = fmaf(cwv.w, acc2[r], s);
        u2[r] = s / (1.f + __expf(-s));
      }
    }
    {
      const int jl = w * 16 + fl;
      unsigned short b1[4] = {f2bf(u1[0]), f2bf(u1[1]), f2bf(u1[2]), f2bf(u1[3])};
      unsigned short b2[4] = {f2bf(u2[0]), f2bf(u2[1]), f2bf(u2[2]), f2bf(u2[3])};
      *(short4b*)&u_ldsb[jl * 40 + fg * 4]      = *(short4b*)b1;
      *(short4b*)&u_ldsb[jl * 40 + 16 + fg * 4] = *(short4b*)b2;
    }
    __syncthreads();               // u_ldsb visible
    {                              // coalesced bf16 uT write (16B/thread)
      const int tq = sk * 8;
      *(short8b*)&uTb[(size_t)(jbase + sj) * BL + bt0 + tq] =
        *(short8b*)&u_ldsb[sj * 40 + tq];
    }
    if (w < 6) {                   // xdbl via MFMA: D[tok][o], K = 128 j this jc
      const float* xrow = &xpw[(size_t)(of * 16 + fl) * DINNER + jbase];
      #pragma unroll
      for (int s = 0; s < 4; ++s) {
        unsigned short ua[8];
        #pragma unroll
        for (int e = 0; e < 8; ++e)
          ua[e] = u_ldsb[(s * 32 + fg * 8 + e) * 40 + tf * 16 + fl];
        const float* wr = xrow + s * 32 + fg * 8;
        float4 w0 = *(const float4*)wr, w1 = *(const float4*)(wr + 4);
        unsigned short wb[8] = {f2bf(w0.x), f2bf(w0.y), f2bf(w0.z), f2bf(w0.w),
                                f2bf(w1.x), f2bf(w1.y), f2bf(w1.z), f2bf(w1.w)};
        xacc = __builtin_amdgcn_mfma_f32_16x16x32_bf16(*(short8b*)ua, *(short8b*)wb,
                                                       xacc, 0, 0, 0);
      }
    }
  }
  if (w < 6) {                     // part[jp][bt0 + tf*16 + fl][of*16 + fg*4 .. +3]
    float4 v = make_float4(xacc[0], xacc[1], xacc[2], xacc[3]);
    *(float4*)&part[(size_t)jp * PSTRIDE +
                    (size_t)(bt0 + tf * 16 + fl) * NPROJ + of * 16 + fg * 4] = v;
  }
}

// ================= kernel 2: chunked scan (2-partial reduce + delta prologue), 4096 blocks =================
__global__ __launch_bounds__(256) void k_scan(const unsigned short* __restrict__ uTb,
                                              const float* __restrict__ part,
                                              const float* __restrict__ dtw,
                                              const float* __restrict__ dtb,
                                              const float* __restrict__ Alog,
                                              float* __restrict__ aprod,
                                              float* __restrict__ hacc) {
  __shared__ float sdt[64][17];
  __shared__ float sB[64][16];
  __shared__ float sdp[16][66][2];
  __shared__ float su[16][68];
  __shared__ float sdtw[16][17];
  __shared__ float sdtb[16];
  const int dblk = blockIdx.x, c = blockIdx.y, b = blockIdx.z;
  const int tid = threadIdx.x;
  const int d0 = dblk * 16;
  const int bt0 = b * LSEQ + c * TCH;
  {
    int tok = tid >> 2, q = (tid & 3) << 2;
    size_t base = (size_t)(bt0 + tok) * NPROJ + q;
    float4 v0 = *(const float4*)&part[base];
    float4 v1 = *(const float4*)&part[base + PSTRIDE];
    sdt[tok][q] = v0.x + v1.x; sdt[tok][q + 1] = v0.y + v1.y;
    sdt[tok][q + 2] = v0.z + v1.z; sdt[tok][q + 3] = v0.w + v1.w;
    float4 w0 = *(const float4*)&part[base + DTRANK];
    float4 w1 = *(const float4*)&part[base + DTRANK + PSTRIDE];
    float4 ww = make_float4(w0.x + w1.x, w0.y + w1.y, w0.z + w1.z, w0.w + w1.w);
    *(float4*)&sB[tok][q] = ww;
    int dl = tid >> 4, t4 = (tid & 15) << 2;
    short4b uv = *(const short4b*)&uTb[(size_t)(d0 + dl) * BL + bt0 + t4];
    su[dl][t4 + 0] = bf2f((unsigned short)uv[0]);
    su[dl][t4 + 1] = bf2f((unsigned short)uv[1]);
    su[dl][t4 + 2] = bf2f((unsigned short)uv[2]);
    su[dl][t4 + 3] = bf2f((unsigned short)uv[3]);
    sdtw[tid >> 4][tid & 15] = dtw[(d0 + (tid >> 4)) * DTRANK + (tid & 15)];
    if (tid < 16) sdtb[tid] = dtb[d0 + tid];
  }
  __syncthreads();
  {
    int tok = tid >> 2, dl4 = (tid & 3) << 2;
    #pragma unroll
    for (int dd = 0; dd < 4; ++dd) {
      int dl = dl4 + dd;
      float a = sdtb[dl];
      #pragma unroll
      for (int r = 0; r < DTRANK; ++r) a = fmaf(sdt[tok][r], sdtw[dl][r], a);
      float dlt = (a > 20.f) ? a : log1pf(__expf(a));
      sdp[dl][tok][0] = dlt;
      sdp[dl][tok][1] = dlt * su[dl][tok];
    }
  }
  __syncthreads();
  const int dl = tid >> 4, n = tid & 15;
  const int d = d0 + dl;
  const float A = -__expf(Alog[d * NSTATE + n]);
  float ap = 1.f, h = 0.f;
  #pragma unroll 8
  for (int tt = 0; tt < TCH; ++tt) {
    float2 dp = *(const float2*)&sdp[dl][tt][0];
    float dA = __expf(dp.x * A);
    h = fmaf(dA, h, dp.y * sB[tt][n]);
    ap *= dA;
  }
  size_t off = (((size_t)b * NCH + c) * DINNER + d) * NSTATE + n;
  aprod[off] = ap;
  hacc[off] = h;
}

// ================= kernel 3: combine chunks + z-gate -> sy =================
__global__ __launch_bounds__(256) void k_combine(const float* __restrict__ aprod,
                                                 const float* __restrict__ hacc,
                                                 const float* __restrict__ part,
                                                 const unsigned short* __restrict__ uTb,
                                                 const float* __restrict__ Dp,
                                                 const float* __restrict__ X,
                                                 const float* __restrict__ ipw,
                                                 float* __restrict__ ybuf) {
  __shared__ float sx[DMODEL];
  const int dblk = blockIdx.x & 31, b = blockIdx.x >> 5;
  const int tid = threadIdx.x;
  const int dl = tid >> 4, n = tid & 15;
  const int d = dblk * 16 + dl;
  sx[tid] = X[((size_t)b * LSEQ + LSEQ - 1) * DMODEL + tid];
  float h = 0.f;
  for (int c = 0; c < NCH; ++c) {
    size_t off = (((size_t)b * NCH + c) * DINNER + d) * NSTATE + n;
    h = fmaf(aprod[off], h, hacc[off]);
  }
  __syncthreads();
  float zp = 0.f;
  {
    const float* zr = &ipw[(size_t)(DINNER + d) * DMODEL + (n << 4)];
    #pragma unroll
    for (int q = 0; q < 4; ++q) {
      float4 w4 = *(const float4*)&zr[q << 2];
      float4 x4 = *(const float4*)&sx[(n << 4) + (q << 2)];
      zp = fmaf(w4.x, x4.x, zp); zp = fmaf(w4.y, x4.y, zp);
      zp = fmaf(w4.z, x4.z, zp); zp = fmaf(w4.w, x4.w, zp);
    }
  }
  const int btL = b * LSEQ + LSEQ - 1;
  size_t cbase = (size_t)btL * NPROJ + DTRANK + NSTATE + n;
  float Cv = part[cbase] + part[cbase + PSTRIDE];
  float v = h * Cv;
  #pragma unroll
  for (int off = 1; off < 16; off <<= 1) {
    v  += __shfl_xor(v, off);
    zp += __shfl_xor(zp, off);
  }
  if (n == 0) {
    float y = v + bf2f(uTb[(size_t)d * BL + btL]) * Dp[d];
    ybuf[b * DINNER + d] = y * zp / (1.f + __expf(-zp));
  }
}

// ================= kernel 4: out = sy @ hwf^T + hb  (one wave per (b,t)) =================
__global__ __launch_bounds__(256) void k_out(const float* __restrict__ sy,
                                             const float* __restrict__ hwf,
                                             const float* __restrict__ hb,
                                             float* __restrict__ out) {
  const int t = blockIdx.x;
  const int b = threadIdx.x >> 6;
  const int lane = threadIdx.x & 63;
  const int k0 = lane << 3;
  const float* yr = &sy[(size_t)b * DINNER + k0];
  const float* wr = &hwf[(size_t)t * DINNER + k0];
  float4 y0 = *(const float4*)yr, y1 = *(const float4*)(yr + 4);
  float4 w0 = *(const float4*)wr, w1 = *(const float4*)(wr + 4);
  float s = y0.x * w0.x + y0.y * w0.y + y0.z * w0.z + y0.w * w0.w
          + y1.x * w1.x + y1.y * w1.y + y1.z * w1.z + y1.w * w1.w;
  #pragma unroll
  for (int off = 1; off < 64; off <<= 1) s += __shfl_xor(s, off);
  if (lane == 0) out[b * HORIZ + t] = s + hb[t];
}

extern "C" void kernel_launch(void* const* d_in, const int* in_sizes, int n_in,
                              void* d_out, int out_size, void* d_ws, size_t ws_size,
                              hipStream_t stream) {
  (void)in_sizes; (void)n_in; (void)out_size; (void)ws_size;
  const float* x    = (const float*)d_in[0];
  const float* ipw  = (const float*)d_in[1];
  const float* cw   = (const float*)d_in[2];
  const float* cb   = (const float*)d_in[3];
  const float* xpw  = (const float*)d_in[4];
  const float* dtw  = (const float*)d_in[5];
  const float* dtb  = (const float*)d_in[6];
  const float* Alog = (const float*)d_in[7];
  const float* Dp   = (const float*)d_in[8];
  const float* opw  = (const float*)d_in[9];
  const float* hw   = (const float*)d_in[10];
  const float* hb   = (const float*)d_in[11];
  float* out = (float*)d_out;
  float* ws  = (float*)d_ws;

  unsigned short* uTb = (unsigned short*)ws;  // 4,194,304 bf16 = 2,097,152 float slots
  float* part  = ws + 2097152;          //   786,432
  float* aprod = ws + 2883584;          // 1,048,576
  float* hacc  = ws + 3932160;          // 1,048,576
  float* ybuf  = ws + 4980736;          //     2,048
  float* hwf   = ws + 4982784;          //    49,152

  k_front<<<576, 512, 0, stream>>>(x, ipw, cw, cb, xpw, opw, hw, uTb, part, hwf);
  k_scan<<<dim3(32, NCH, BATCH), 256, 0, stream>>>(uTb, part, dtw, dtb, Alog, aprod, hacc);
  k_combine<<<128, 256, 0, stream>>>(aprod, hacc, part, uTb, Dp, x, ipw, ybuf);
  k_out<<<HORIZ, 256, 0, stream>>>(ybuf, hwf, hb, out);
}

// Round 18
// 72.453 us; speedup vs baseline: 1.0415x; 1.0415x over previous
//
#include <hip/hip_runtime.h>
#include <math.h>

#define BATCH 4
#define LSEQ 2048
#define BL (BATCH*LSEQ)        // 8192
#define DMODEL 256
#define DINNER 512
#define NSTATE 16
#define DTRANK 16
#define NPROJ 48               // DTRANK + 2*NSTATE
#define HORIZ 96
#define NCH 32                 // scan chunks
#define TCH (LSEQ/NCH)         // 64
#define PSTRIDE (BL*NPROJ)     // 393216 (part jp-stride)

typedef __attribute__((ext_vector_type(8))) short short8b;  // 8 bf16
typedef __attribute__((ext_vector_type(4))) short short4b;  // 4 bf16
typedef __attribute__((ext_vector_type(4))) float f32x4;

__device__ __forceinline__ unsigned short f2bf(float f) {
  unsigned u = __float_as_uint(f);
  u += 0x7FFF + ((u >> 16) & 1);          // round-to-nearest-even
  return (unsigned short)(u >> 16);
}
__device__ __forceinline__ float bf2f(unsigned short h) {
  return __uint_as_float(((unsigned)h) << 16);
}

// ===== kernel 1 (fused): in_proj(x half, bf16 MFMA) + conv + silu -> uT(bf16) ; x_dbl via MFMA =====
// grid 512 main (btc = bx&255, jp = bx>>8 so jp pairs share an XCD) + 64 hwf side-job; 512 thr.
// LDS 48.6KB -> 3 blocks/CU.  [verified best: R13/R16, 72.5-72.9 us]
__global__ __launch_bounds__(512) void k_front(const float* __restrict__ X,
                                               const float* __restrict__ W,
                                               const float* __restrict__ cw,
                                               const float* __restrict__ cb,
                                               const float* __restrict__ xpw,
                                               const float* __restrict__ opw,
                                               const float* __restrict__ hw,
                                               unsigned short* __restrict__ uTb,
                                               float* __restrict__ part,
                                               float* __restrict__ hwf) {
  __shared__ unsigned short sBX[48 * 264];    // [tok][33*8] bf16, row 528B (25.3KB)
  __shared__ unsigned short sw2b[48 * 136];   // [o][k_local] bf16, row 272B (13.1KB)
  __shared__ unsigned short u_ldsb[128 * 40]; // [j_local][tok] bf16, row 80B (10.2KB)
  const int tid = threadIdx.x;
  const int bx = blockIdx.x;
  if (bx >= 512) {                 // ---- side-job: hwf[t][k] = sum_m hw[t][m]*opw[m][k]
    const int fid = bx - 512;      // 0..63
    const int k0 = fid * 8;
    float* scratch = (float*)sBX;  // [m 0..255][8] fp32 (8KB of the 25KB region)
    {
      int m = tid >> 1;            // opw rows = DMODEL = 256
      int half = (tid & 1) << 2;
      *(float4*)&scratch[m * 8 + half] =
        *(const float4*)&opw[(size_t)m * DINNER + k0 + half];
    }
    __syncthreads();
    for (int u = tid; u < HORIZ * 8; u += 512) {
      int t = u >> 3, kk = u & 7;
      const float* hr = &hw[(size_t)t * DMODEL];
      float acc = 0.f;
      #pragma unroll 8
      for (int m = 0; m < DMODEL; ++m) acc = fmaf(hr[m], scratch[m*8 + kk], acc);
      hwf[(size_t)t * DINNER + k0 + kk] = acc;
    }
    return;
  }
  const int btc = bx & 255;        // token tile
  const int jp  = bx >> 8;         // j-half; pair (bx, bx+256) -> same XCD (256 % 8 == 0)
  const int bt0 = btc * 32;
  const bool edge0 = ((bt0 & (LSEQ - 1)) == 0);
  const int lane = tid & 63;
  const int w  = tid >> 6;         // wave 0..7
  const int fl = lane & 15;
  const int fg = lane >> 4;        // 0..3
  // ---- phase 0: stage X tile bf16, tokens [bt0-16, bt0+32): sBX[tok][ko*8]
  for (int u = tid; u < 1536; u += 512) {
    int tok = u >> 5, ko = u & 31;
    int g = bt0 - 16 + tok;
    if (g < 0) g = 0;              // clamped rows feed only the (zeroed) halo frag
    const float* xr = &X[(size_t)g * DMODEL + ko * 8];
    float4 a = *(const float4*)xr, b = *(const float4*)(xr + 4);
    unsigned short t8[8] = {f2bf(a.x), f2bf(a.y), f2bf(a.z), f2bf(a.w),
                            f2bf(b.x), f2bf(b.y), f2bf(b.z), f2bf(b.w)};
    *(short8b*)&sBX[tok * 264 + ko * 8] = *(short8b*)t8;
  }
  const int sj = tid >> 2;         // uT write: j row
  const int sk = tid & 3;          // uT write: token-octet
  const int tf = w & 1;            // xdbl: token-frag (w<6)
  const int of = w >> 1;           // xdbl: o-frag
  f32x4 xacc = {0.f, 0.f, 0.f, 0.f};
  for (int jc = 0; jc < 2; ++jc) {
    const int jbase = jp * 256 + jc * 128;
    __syncthreads();               // prev jc done with u_ldsb+sw2b; jc=0: sBX visible
    // stage sw2b (xpw chunk, bf16) — separate region, overlaps MFMA phase
    for (int u = tid; u < 768; u += 512) {
      int o = u >> 4, k8 = (u & 15) * 8;
      const float* src = &xpw[(size_t)o * DINNER + jbase + k8];
      float4 a = *(const float4*)src, b = *(const float4*)(src + 4);
      unsigned short t8[8] = {f2bf(a.x), f2bf(a.y), f2bf(a.z), f2bf(a.w),
                              f2bf(b.x), f2bf(b.y), f2bf(b.z), f2bf(b.w)};
      *(short8b*)&sw2b[o * 136 + k8] = *(short8b*)t8;
    }
    // W fragments -> registers (L2-resident; no LDS, no barriers)
    short8b aw[8];
    {
      const float* wrow = &W[(size_t)(jbase + w * 16 + fl) * DMODEL + fg * 8];
      #pragma unroll
      for (int ks = 0; ks < 8; ++ks) {
        float4 a = *(const float4*)(wrow + ks * 32);
        float4 b = *(const float4*)(wrow + ks * 32 + 4);
        unsigned short t8[8] = {f2bf(a.x), f2bf(a.y), f2bf(a.z), f2bf(a.w),
                                f2bf(b.x), f2bf(b.y), f2bf(b.z), f2bf(b.w)};
        aw[ks] = *(short8b*)t8;
      }
    }
    f32x4 acc0 = {0,0,0,0}, acc1 = {0,0,0,0}, acc2 = {0,0,0,0};
    #pragma unroll
    for (int ks = 0; ks < 8; ++ks) {
      const int kcol = (ks * 4 + fg) * 8;
      short8b x0 = *(short8b*)&sBX[(fl)      * 264 + kcol];
      short8b x1 = *(short8b*)&sBX[(16 + fl) * 264 + kcol];
      short8b x2 = *(short8b*)&sBX[(32 + fl) * 264 + kcol];
      acc0 = __builtin_amdgcn_mfma_f32_16x16x32_bf16(x0, aw[ks], acc0, 0, 0, 0);
      acc1 = __builtin_amdgcn_mfma_f32_16x16x32_bf16(x1, aw[ks], acc1, 0, 0, 0);
      acc2 = __builtin_amdgcn_mfma_f32_16x16x32_bf16(x2, aw[ks], acc2, 0, 0, 0);
    }
    // ---- conv + silu in registers (verified structure)
    if (edge0) acc0 = (f32x4){0,0,0,0};   // zero-pad halo at batch starts
    const int j = jbase + w * 16 + fl;
    const float4 cwv = *(const float4*)&cw[j * 4];
    const float cbv = cb[j];
    float u1[4], u2[4];
    {
      float s3a = __shfl(acc1[3], lane - 16), s3b = __shfl(acc0[3], lane + 48);
      float s2a = __shfl(acc1[2], lane - 16), s2b = __shfl(acc0[2], lane + 48);
      float s1a = __shfl(acc1[1], lane - 16), s1b = __shfl(acc0[1], lane + 48);
      float p1 = fg ? s3a : s3b, p2 = fg ? s2a : s2b, p3 = fg ? s1a : s1b;
      float xm1[4] = {p1, acc1[0], acc1[1], acc1[2]};
      float xm2[4] = {p2, p1, acc1[0], acc1[1]};
      float xm3[4] = {p3, p2, p1, acc1[0]};
      #pragma unroll
      for (int r = 0; r < 4; ++r) {
        float s = cbv;
        s = fmaf(cwv.x, xm3[r], s); s = fmaf(cwv.y, xm2[r], s);
        s = fmaf(cwv.z, xm1[r], s); s = fmaf(cwv.w, acc1[r], s);
        u1[r] = s / (1.f + __expf(-s));
      }
    }
    {
      float s3a = __shfl(acc2[3], lane - 16), s3b = __shfl(acc1[3], lane + 48);
      float s2a = __shfl(acc2[2], lane - 16), s2b = __shfl(acc1[2], lane + 48);
      float s1a = __shfl(acc2[1], lane - 16), s1b = __shfl(acc1[1], lane + 48);
      float p1 = fg ? s3a : s3b, p2 = fg ? s2a : s2b, p3 = fg ? s1a : s1b;
      float xm1[4] = {p1, acc2[0], acc2[1], acc2[2]};
      float xm2[4] = {p2, p1, acc2[0], acc2[1]};
      float xm3[4] = {p3, p2, p1, acc2[0]};
      #pragma unroll
      for (int r = 0; r < 4; ++r) {
        float s = cbv;
        s = fmaf(cwv.x, xm3[r], s); s = fmaf(cwv.y, xm2[r], s);
        s = fmaf(cwv.z, xm1[r], s); s = fmaf(cwv.w, acc2[r], s);
        u2[r] = s / (1.f + __expf(-s));
      }
    }
    {
      const int jl = w * 16 + fl;
      unsigned short b1[4] = {f2bf(u1[0]), f2bf(u1[1]), f2bf(u1[2]), f2bf(u1[3])};
      unsigned short b2[4] = {f2bf(u2[0]), f2bf(u2[1]), f2bf(u2[2]), f2bf(u2[3])};
      *(short4b*)&u_ldsb[jl * 40 + fg * 4]      = *(short4b*)b1;
      *(short4b*)&u_ldsb[jl * 40 + 16 + fg * 4] = *(short4b*)b2;
    }
    __syncthreads();               // u_ldsb + sw2b visible
    {                              // coalesced bf16 uT write (16B/thread)
      const int tq = sk * 8;
      *(short8b*)&uTb[(size_t)(jbase + sj) * BL + bt0 + tq] =
        *(short8b*)&u_ldsb[sj * 40 + tq];
    }
    if (w < 6) {                   // xdbl via MFMA: D[tok][o], K = 128 j this jc
      #pragma unroll
      for (int s = 0; s < 4; ++s) {
        unsigned short ua[8];
        #pragma unroll
        for (int e = 0; e < 8; ++e)
          ua[e] = u_ldsb[(s * 32 + fg * 8 + e) * 40 + tf * 16 + fl];
        short8b wb = *(short8b*)&sw2b[(of * 16 + fl) * 136 + s * 32 + fg * 8];
        xacc = __builtin_amdgcn_mfma_f32_16x16x32_bf16(*(short8b*)ua, wb,
                                                       xacc, 0, 0, 0);
      }
    }
  }
  if (w < 6) {                     // part[jp][bt0 + tf*16 + fl][of*16 + fg*4 .. +3]
    float4 v = make_float4(xacc[0], xacc[1], xacc[2], xacc[3]);
    *(float4*)&part[(size_t)jp * PSTRIDE +
                    (size_t)(bt0 + tf * 16 + fl) * NPROJ + of * 16 + fg * 4] = v;
  }
}

// ================= kernel 2: chunked scan (2-partial reduce + delta prologue), 4096 blocks =================
__global__ __launch_bounds__(256) void k_scan(const unsigned short* __restrict__ uTb,
                                              const float* __restrict__ part,
                                              const float* __restrict__ dtw,
                                              const float* __restrict__ dtb,
                                              const float* __restrict__ Alog,
                                              float* __restrict__ aprod,
                                              float* __restrict__ hacc) {
  __shared__ float sdt[64][17];
  __shared__ float sB[64][16];
  __shared__ float sdp[16][66][2];
  __shared__ float su[16][68];
  __shared__ float sdtw[16][17];
  __shared__ float sdtb[16];
  const int dblk = blockIdx.x, c = blockIdx.y, b = blockIdx.z;
  const int tid = threadIdx.x;
  const int d0 = dblk * 16;
  const int bt0 = b * LSEQ + c * TCH;
  {
    int tok = tid >> 2, q = (tid & 3) << 2;
    size_t base = (size_t)(bt0 + tok) * NPROJ + q;
    float4 v0 = *(const float4*)&part[base];
    float4 v1 = *(const float4*)&part[base + PSTRIDE];
    sdt[tok][q] = v0.x + v1.x; sdt[tok][q + 1] = v0.y + v1.y;
    sdt[tok][q + 2] = v0.z + v1.z; sdt[tok][q + 3] = v0.w + v1.w;
    float4 w0 = *(const float4*)&part[base + DTRANK];
    float4 w1 = *(const float4*)&part[base + DTRANK + PSTRIDE];
    float4 ww = make_float4(w0.x + w1.x, w0.y + w1.y, w0.z + w1.z, w0.w + w1.w);
    *(float4*)&sB[tok][q] = ww;
    int dl = tid >> 4, t4 = (tid & 15) << 2;
    short4b uv = *(const short4b*)&uTb[(size_t)(d0 + dl) * BL + bt0 + t4];
    su[dl][t4 + 0] = bf2f((unsigned short)uv[0]);
    su[dl][t4 + 1] = bf2f((unsigned short)uv[1]);
    su[dl][t4 + 2] = bf2f((unsigned short)uv[2]);
    su[dl][t4 + 3] = bf2f((unsigned short)uv[3]);
    sdtw[tid >> 4][tid & 15] = dtw[(d0 + (tid >> 4)) * DTRANK + (tid & 15)];
    if (tid < 16) sdtb[tid] = dtb[d0 + tid];
  }
  __syncthreads();
  {
    int tok = tid >> 2, dl4 = (tid & 3) << 2;
    #pragma unroll
    for (int dd = 0; dd < 4; ++dd) {
      int dl = dl4 + dd;
      float a = sdtb[dl];
      #pragma unroll
      for (int r = 0; r < DTRANK; ++r) a = fmaf(sdt[tok][r], sdtw[dl][r], a);
      float dlt = (a > 20.f) ? a : log1pf(__expf(a));
      sdp[dl][tok][0] = dlt;
      sdp[dl][tok][1] = dlt * su[dl][tok];
    }
  }
  __syncthreads();
  const int dl = tid >> 4, n = tid & 15;
  const int d = d0 + dl;
  const float A = -__expf(Alog[d * NSTATE + n]);
  float ap = 1.f, h = 0.f;
  #pragma unroll 8
  for (int tt = 0; tt < TCH; ++tt) {
    float2 dp = *(const float2*)&sdp[dl][tt][0];
    float dA = __expf(dp.x * A);
    h = fmaf(dA, h, dp.y * sB[tt][n]);
    ap *= dA;
  }
  size_t off = (((size_t)b * NCH + c) * DINNER + d) * NSTATE + n;
  aprod[off] = ap;
  hacc[off] = h;
}

// ================= kernel 3: combine chunks + z-gate -> sy =================
__global__ __launch_bounds__(256) void k_combine(const float* __restrict__ aprod,
                                                 const float* __restrict__ hacc,
                                                 const float* __restrict__ part,
                                                 const unsigned short* __restrict__ uTb,
                                                 const float* __restrict__ Dp,
                                                 const float* __restrict__ X,
                                                 const float* __restrict__ ipw,
                                                 float* __restrict__ ybuf) {
  __shared__ float sx[DMODEL];
  const int dblk = blockIdx.x & 31, b = blockIdx.x >> 5;
  const int tid = threadIdx.x;
  const int dl = tid >> 4, n = tid & 15;
  const int d = dblk * 16 + dl;
  sx[tid] = X[((size_t)b * LSEQ + LSEQ - 1) * DMODEL + tid];
  float h = 0.f;
  for (int c = 0; c < NCH; ++c) {
    size_t off = (((size_t)b * NCH + c) * DINNER + d) * NSTATE + n;
    h = fmaf(aprod[off], h, hacc[off]);
  }
  __syncthreads();
  float zp = 0.f;
  {
    const float* zr = &ipw[(size_t)(DINNER + d) * DMODEL + (n << 4)];
    #pragma unroll
    for (int q = 0; q < 4; ++q) {
      float4 w4 = *(const float4*)&zr[q << 2];
      float4 x4 = *(const float4*)&sx[(n << 4) + (q << 2)];
      zp = fmaf(w4.x, x4.x, zp); zp = fmaf(w4.y, x4.y, zp);
      zp = fmaf(w4.z, x4.z, zp); zp = fmaf(w4.w, x4.w, zp);
    }
  }
  const int btL = b * LSEQ + LSEQ - 1;
  size_t cbase = (size_t)btL * NPROJ + DTRANK + NSTATE + n;
  float Cv = part[cbase] + part[cbase + PSTRIDE];
  float v = h * Cv;
  #pragma unroll
  for (int off = 1; off < 16; off <<= 1) {
    v  += __shfl_xor(v, off);
    zp += __shfl_xor(zp, off);
  }
  if (n == 0) {
    float y = v + bf2f(uTb[(size_t)d * BL + btL]) * Dp[d];
    ybuf[b * DINNER + d] = y * zp / (1.f + __expf(-zp));
  }
}

// ================= kernel 4: out = sy @ hwf^T + hb  (one wave per (b,t)) =================
__global__ __launch_bounds__(256) void k_out(const float* __restrict__ sy,
                                             const float* __restrict__ hwf,
                                             const float* __restrict__ hb,
                                             float* __restrict__ out) {
  const int t = blockIdx.x;
  const int b = threadIdx.x >> 6;
  const int lane = threadIdx.x & 63;
  const int k0 = lane << 3;
  const float* yr = &sy[(size_t)b * DINNER + k0];
  const float* wr = &hwf[(size_t)t * DINNER + k0];
  float4 y0 = *(const float4*)yr, y1 = *(const float4*)(yr + 4);
  float4 w0 = *(const float4*)wr, w1 = *(const float4*)(wr + 4);
  float s = y0.x * w0.x + y0.y * w0.y + y0.z * w0.z + y0.w * w0.w
          + y1.x * w1.x + y1.y * w1.y + y1.z * w1.z + y1.w * w1.w;
  #pragma unroll
  for (int off = 1; off < 64; off <<= 1) s += __shfl_xor(s, off);
  if (lane == 0) out[b * HORIZ + t] = s + hb[t];
}

extern "C" void kernel_launch(void* const* d_in, const int* in_sizes, int n_in,
                              void* d_out, int out_size, void* d_ws, size_t ws_size,
                              hipStream_t stream) {
  (void)in_sizes; (void)n_in; (void)out_size; (void)ws_size;
  const float* x    = (const float*)d_in[0];
  const float* ipw  = (const float*)d_in[1];
  const float* cw   = (const float*)d_in[2];
  const float* cb   = (const float*)d_in[3];
  const float* xpw  = (const float*)d_in[4];
  const float* dtw  = (const float*)d_in[5];
  const float* dtb  = (const float*)d_in[6];
  const float* Alog = (const float*)d_in[7];
  const float* Dp   = (const float*)d_in[8];
  const float* opw  = (const float*)d_in[9];
  const float* hw   = (const float*)d_in[10];
  const float* hb   = (const float*)d_in[11];
  float* out = (float*)d_out;
  float* ws  = (float*)d_ws;

  unsigned short* uTb = (unsigned short*)ws;  // 4,194,304 bf16 = 2,097,152 float slots
  float* part  = ws + 2097152;          //   786,432
  float* aprod = ws + 2883584;          // 1,048,576
  float* hacc  = ws + 3932160;          // 1,048,576
  float* ybuf  = ws + 4980736;          //     2,048
  float* hwf   = ws + 4982784;          //    49,152

  k_front<<<576, 512, 0, stream>>>(x, ipw, cw, cb, xpw, opw, hw, uTb, part, hwf);
  k_scan<<<dim3(32, NCH, BATCH), 256, 0, stream>>>(uTb, part, dtw, dtb, Alog, aprod, hacc);
  k_combine<<<128, 256, 0, stream>>>(aprod, hacc, part, uTb, Dp, x, ipw, ybuf);
  k_out<<<HORIZ, 256, 0, stream>>>(ybuf, hwf, hb, out);
}